// Round 7
// baseline (425.689 us; speedup 1.0000x reference)
//
#include <hip/hip_runtime.h>
#include <hip/hip_cooperative_groups.h>
#include <hip/hip_bf16.h>

namespace cg = cooperative_groups;

#define NB 64
#define NC 256
#define NL 2048
#define NH 8
#define KW 3
#define LP (NL - KW + 1)  // 2046
#define NCHUNK 8
#define CPC (NC / NCHUNK)  // 32 channels per chunk

typedef float v4f __attribute__((ext_vector_type(4)));

// monotonic float->uint key: order(u) == order(x)
__device__ __forceinline__ unsigned fkey(float x) {
  unsigned b = __float_as_uint(x);
  return (b & 0x80000000u) ? ~b : (b | 0x80000000u);
}

// All 4 proven phases in ONE cooperative kernel with grid.sync() between.
// Phase bodies are identical to the R6 kernels; virtual-block grid-stride
// loops make any grid size correct.
__global__ __launch_bounds__(256, 4) void fused_all(
    const float* __restrict__ src, const float* __restrict__ conv_w,
    const float* __restrict__ conv_b, const float* __restrict__ bn_gamma,
    const float* __restrict__ bn_beta, const float* __restrict__ comb_w,
    const float* __restrict__ comb_b, const int* __restrict__ kptr,
    float* __restrict__ part, float* __restrict__ xi,
    float* __restrict__ gate, float* __restrict__ out) {
  cg::grid_group gg = cg::this_grid();
  const int t = threadIdx.x;
  const int bx = blockIdx.x;
  const int lane = t & 63, wid = t >> 6;

  __shared__ float xs[LP];
  __shared__ float smp[NL + 2];
  __shared__ int hist[256];
  __shared__ float rs[8];
  __shared__ float fbc[2];
  __shared__ int irs[8];
  __shared__ int ibc[4];

  // ---- phase 1: conv partial sums (virtual grid (2, NB, NCHUNK) = 1024) ----
  for (int v = bx; v < 2 * NB * NCHUNK; v += gridDim.x) {
    const int l0 = (v & 1) * 1024 + t * 4;
    const int b = (v >> 1) & (NB - 1);
    const int cc = v >> 7;
    const int c0 = cc * CPC;
    float acc[NH][4];
#pragma unroll
    for (int h = 0; h < NH; ++h)
#pragma unroll
      for (int j = 0; j < 4; ++j) acc[h][j] = 0.f;
    const float* sp = src + ((size_t)b * NC + c0) * NL + l0;
    const bool tail = (lane == 63) && (l0 + 5 < NL);
#pragma unroll 2
    for (int c = 0; c < CPC; ++c) {
      v4f vv = *(const v4f*)sp;
      float e0 = 0.f, e1 = 0.f;
      if (tail) { e0 = sp[4]; e1 = sp[5]; }
      sp += NL;
      float n0 = __shfl_down(vv.x, 1);
      float n1 = __shfl_down(vv.y, 1);
      if (lane == 63) { n0 = e0; n1 = e1; }
      float s0 = vv.x, s1 = vv.y, s2 = vv.z, s3 = vv.w, s4 = n0, s5 = n1;
#pragma unroll
      for (int h = 0; h < NH; ++h) {
        const float* w = conv_w + (h * NC + c0 + c) * KW;  // uniform -> s_load
        const float w0 = w[0], w1 = w[1], w2 = w[2];
        acc[h][0] = fmaf(s0, w0, fmaf(s1, w1, fmaf(s2, w2, acc[h][0])));
        acc[h][1] = fmaf(s1, w0, fmaf(s2, w1, fmaf(s3, w2, acc[h][1])));
        acc[h][2] = fmaf(s2, w0, fmaf(s3, w1, fmaf(s4, w2, acc[h][2])));
        acc[h][3] = fmaf(s3, w0, fmaf(s4, w1, fmaf(s5, w2, acc[h][3])));
      }
    }
#pragma unroll
    for (int h = 0; h < NH; ++h) {
      float* pr = part + ((size_t)(b * NH + h) * NCHUNK + cc) * NL + l0;
      if (l0 + 3 < LP) {
        *(v4f*)pr = *(v4f*)acc[h];
      } else {
#pragma unroll
        for (int j = 0; j < 4; ++j)
          if (l0 + j < LP) pr[j] = acc[h][j];
      }
    }
  }
  gg.sync();

  // ---- phase 2: select per (b,h) row (virtual grid NB*NH = 512) ----
  for (int v = bx; v < NB * NH; v += gridDim.x) {
    const int h = v & (NH - 1);
    const float cb = conv_b[h];
    const float* p0 = part + (size_t)v * NCHUNK * NL;
    float s1 = 0.f, s2 = 0.f;
    for (int i = t; i < LP; i += 256) {
      float v0 = p0[i]          + p0[i + NL];
      float v1 = p0[i + 2 * NL] + p0[i + 3 * NL];
      float v2 = p0[i + 4 * NL] + p0[i + 5 * NL];
      float v3 = p0[i + 6 * NL] + p0[i + 7 * NL];
      float val = ((v0 + v1) + (v2 + v3)) + cb;
      xs[i] = val;
      s1 += val;
      s2 += val * val;
    }
#pragma unroll
    for (int off = 32; off > 0; off >>= 1) {
      s1 += __shfl_down(s1, off);
      s2 += __shfl_down(s2, off);
    }
    if (lane == 0) { rs[wid] = s1; rs[wid + 4] = s2; }
    __syncthreads();
    if (t == 0) {
      float S = rs[0] + rs[1] + rs[2] + rs[3];
      float Q = rs[4] + rs[5] + rs[6] + rs[7];
      float mu = S / (float)LP;
      float var = Q / (float)LP - mu * mu;
      float inv = rsqrtf(var + 1e-5f);
      float sc = bn_gamma[h] * inv;
      fbc[0] = sc;
      fbc[1] = bn_beta[h] - mu * sc;
    }
    __syncthreads();
    {
      const float sc = fbc[0], sh = fbc[1];
      for (int i = t; i < LP; i += 256) xs[i] = fmaf(xs[i], sc, sh);
    }
    int kk = kptr[0];
    const int ktot = kk;
    unsigned prefix = 0, pm = 0;
    for (int pass = 0; pass < 4; ++pass) {
      const int shift = 24 - 8 * pass;
      hist[t] = 0;
      __syncthreads();
      for (int i = t; i < LP; i += 256) {
        unsigned u = fkey(xs[i]);
        if ((u & pm) == prefix) atomicAdd(&hist[(u >> shift) & 255], 1);
      }
      __syncthreads();
      if (t < 64) {  // wave 0: suffix-scan 256 bins, 4 bins/lane
        const int h0 = hist[t * 4 + 0], h1 = hist[t * 4 + 1];
        const int h2 = hist[t * 4 + 2], h3 = hist[t * 4 + 3];
        const int g = h0 + h1 + h2 + h3;
        int sfx = g;
#pragma unroll
        for (int off = 1; off < 64; off <<= 1) {
          int o = __shfl(sfx, (t + off) & 63);
          if (t + off < 64) sfx += o;
        }
        const int A = sfx - g;
        const int s3 = A + h3, s2i = s3 + h2, s1i = s2i + h1, s0i = s1i + h0;
        int mybin = -1, mykk = 0;
        if (s0i >= kk && s0i - h0 < kk) { mybin = t * 4 + 0; mykk = kk - (s0i - h0); }
        if (s1i >= kk && s1i - h1 < kk) { mybin = t * 4 + 1; mykk = kk - (s1i - h1); }
        if (s2i >= kk && s2i - h2 < kk) { mybin = t * 4 + 2; mykk = kk - (s2i - h2); }
        if (s3  >= kk && s3  - h3 < kk) { mybin = t * 4 + 3; mykk = kk - (s3 - h3); }
        if (mybin >= 0) { ibc[0] = mybin; ibc[1] = mykk; }
      }
      __syncthreads();
      prefix |= ((unsigned)ibc[0]) << shift;
      pm |= 255u << shift;
      kk = ibc[1];
    }
    const unsigned T = prefix;

    int cgt = 0, ceq = 0;
    for (int i = t; i < LP; i += 256) {
      unsigned u = fkey(xs[i]);
      cgt += (u > T);
      ceq += (u == T);
    }
#pragma unroll
    for (int off = 32; off > 0; off >>= 1) {
      cgt += __shfl_down(cgt, off);
      ceq += __shfl_down(ceq, off);
    }
    if (lane == 0) { irs[wid] = cgt; irs[wid + 4] = ceq; }
    __syncthreads();
    if (t == 0) {
      ibc[2] = irs[0] + irs[1] + irs[2] + irs[3];
      ibc[3] = irs[4] + irs[5] + irs[6] + irs[7];
    }
    __syncthreads();
    const int need_eq = ktot - ibc[2];
    const bool tie = (ibc[3] != need_eq);

    for (int i = t; i < LP; i += 256) {
      float x = xs[i];
      unsigned u = fkey(x);
      bool sel = tie ? (u > T) : (u >= T);
      smp[i + 2] = sel ? 1.f / (1.f + __expf(-x)) : 0.f;
    }
    if (t < 2) { smp[t] = 0.f; smp[NL + t] = 0.f; }
    __syncthreads();
    if (tie && t == 0) {  // rare: stable lowest-index-first like lax.top_k
      int taken = 0;
      for (int i = 0; i < LP && taken < need_eq; ++i) {
        float x = xs[i];
        if (fkey(x) == T) { smp[i + 2] = 1.f / (1.f + __expf(-x)); ++taken; }
      }
    }
    __syncthreads();

    const float cw = comb_w[h] * (1.0f / (float)KW);
    float* row = xi + (size_t)v * NL;
    for (int l = t; l < NL; l += 256)
      row[l] = cw * ((smp[l + 2] + smp[l + 1]) + smp[l]);
    __syncthreads();  // protect shared arrays before next virtual block
  }
  gg.sync();

  // ---- phase 3: gate combine (virtual grid 128) ----
  for (int v = bx; v < (NB * NL) / (4 * 256); v += gridDim.x) {
    const int idx = v * 256 + t;
    const int b = idx >> 9;
    const int l4 = idx & 511;
    const v4f* p = (const v4f*)(xi + (size_t)b * NH * NL) + l4;
    v4f s = p[0];
#pragma unroll
    for (int h = 1; h < NH; ++h) s += p[(size_t)h * (NL / 4)];
    ((v4f*)gate)[idx] = s;
  }
  gg.sync();

  // ---- phase 4: scale (thread grid-stride) ----
  {
    const size_t total = (size_t)NB * NC * NL / 4;
    const float cb2 = comb_b[0];
    for (size_t idx = (size_t)bx * 256 + t; idx < total;
         idx += (size_t)gridDim.x * 256) {
      const size_t e = idx * 4;
      const int l = (int)(e & (NL - 1));
      const int b = (int)(e >> 19);  // C*L = 2^19
      v4f sv = ((const v4f*)src)[idx];
      v4f gv = *(const v4f*)(gate + (size_t)b * NL + l);
      v4f ov;
      ov.x = fmaf(sv.x, gv.x, cb2);
      ov.y = fmaf(sv.y, gv.y, cb2);
      ov.z = fmaf(sv.z, gv.z, cb2);
      ov.w = fmaf(sv.w, gv.w, cb2);
      __builtin_nontemporal_store(ov, (v4f*)out + idx);
    }
  }
}

extern "C" void kernel_launch(void* const* d_in, const int* in_sizes, int n_in,
                              void* d_out, int out_size, void* d_ws, size_t ws_size,
                              hipStream_t stream) {
  const float* src = (const float*)d_in[0];
  const float* conv_w = (const float*)d_in[1];
  const float* conv_b = (const float*)d_in[2];
  const float* bn_gamma = (const float*)d_in[3];
  const float* bn_beta = (const float*)d_in[4];
  const float* comb_w = (const float*)d_in[5];
  const float* comb_b = (const float*)d_in[6];
  const int* kptr = (const int*)d_in[7];
  float* out = (float*)d_out;

  float* xi = (float*)d_ws;                 // NB*NH*NL floats (4 MB)
  float* gate = xi + (size_t)NB * NH * NL;  // NB*NL floats (512 KB)
  float* part = out;                        // 32 MB scratch inside d_out
                                            // (consumed in phase 2, then fully
                                            //  overwritten by phase 4)

  int maxAct = 0;
  if (hipOccupancyMaxActiveBlocksPerMultiprocessor(&maxAct, fused_all, 256, 0)
          != hipSuccess || maxAct < 1)
    maxAct = 2;  // conservative fallback
  int grid = maxAct * 256;  // 256 CUs on gfx950
  if (grid > 1024) grid = 1024;

  void* args[] = {&src, &conv_w, &conv_b, &bn_gamma, &bn_beta, &comb_w,
                  &comb_b, &kptr, &part, &xi, &gate, &out};
  hipLaunchCooperativeKernel((const void*)fused_all, dim3(grid), dim3(256),
                             args, 0, stream);
}

// Round 8
// 92.673 us; speedup vs baseline: 4.5935x; 4.5935x over previous
//
#include <hip/hip_runtime.h>
#include <hip/hip_bf16.h>

#define NB 64
#define NC 256
#define NL 2048
#define NH 8
#define KW 3
#define LP (NL - KW + 1)  // 2046
#define NCHUNK 8
#define CPC (NC / NCHUNK)  // 32 channels per chunk

typedef float v4f __attribute__((ext_vector_type(4)));

// monotonic float->uint key: order(u) == order(x)
__device__ __forceinline__ unsigned fkey(float x) {
  unsigned b = __float_as_uint(x);
  return (b & 0x80000000u) ? ~b : (b | 0x80000000u);
}

// Kernel 1 (R4/R6-proven, unchanged): conv1d partial sums. Each thread: 4
// consecutive l outputs x 8 heads from ONE float4 load per channel
// (+shuffle halo). Grid (2, NB, NCHUNK) = 1024 blocks.
__global__ __launch_bounds__(256) void conv_partial(
    const float* __restrict__ src, const float* __restrict__ conv_w,
    float* __restrict__ part) {
  const int t = threadIdx.x;
  const int lane = t & 63;
  const int l0 = blockIdx.x * 1024 + t * 4;
  const int b = blockIdx.y;
  const int cc = blockIdx.z;
  const int c0 = cc * CPC;

  float acc[NH][4];
#pragma unroll
  for (int h = 0; h < NH; ++h)
#pragma unroll
    for (int j = 0; j < 4; ++j) acc[h][j] = 0.f;

  const float* sp = src + ((size_t)b * NC + c0) * NL + l0;
  const bool tail = (lane == 63) && (l0 + 5 < NL);
#pragma unroll 2
  for (int c = 0; c < CPC; ++c) {
    v4f v = *(const v4f*)sp;
    float e0 = 0.f, e1 = 0.f;
    if (tail) { e0 = sp[4]; e1 = sp[5]; }
    sp += NL;
    float n0 = __shfl_down(v.x, 1);
    float n1 = __shfl_down(v.y, 1);
    if (lane == 63) { n0 = e0; n1 = e1; }
    float s0 = v.x, s1 = v.y, s2 = v.z, s3 = v.w, s4 = n0, s5 = n1;
#pragma unroll
    for (int h = 0; h < NH; ++h) {
      const float* w = conv_w + (h * NC + c0 + c) * KW;  // uniform -> s_load
      const float w0 = w[0], w1 = w[1], w2 = w[2];
      acc[h][0] = fmaf(s0, w0, fmaf(s1, w1, fmaf(s2, w2, acc[h][0])));
      acc[h][1] = fmaf(s1, w0, fmaf(s2, w1, fmaf(s3, w2, acc[h][1])));
      acc[h][2] = fmaf(s2, w0, fmaf(s3, w1, fmaf(s4, w2, acc[h][2])));
      acc[h][3] = fmaf(s3, w0, fmaf(s4, w1, fmaf(s5, w2, acc[h][3])));
    }
  }
#pragma unroll
  for (int h = 0; h < NH; ++h) {
    float* pr = part + ((size_t)(b * NH + h) * NCHUNK + cc) * NL + l0;
    if (l0 + 3 < LP) {
      *(v4f*)pr = *(v4f*)acc[h];
    } else {
#pragma unroll
      for (int j = 0; j < 4; ++j)
        if (l0 + j < LP) pr[j] = acc[h][j];
    }
  }
}

// Kernel 2 (R6-proven, unchanged): one 256-thread block per (b,h). Sum the 8
// partials (+bias) into LDS (part is L3-resident), BN stats, exact
// radix-select of the k-th largest (stable ties like lax.top_k), sigmoid
// mask, 3-tap box sum, write cw*M into the xi row.
__global__ __launch_bounds__(256) void select_block(
    const float* __restrict__ part, float* __restrict__ xi,
    const float* __restrict__ conv_b, const float* __restrict__ bn_gamma,
    const float* __restrict__ bn_beta, const float* __restrict__ comb_w,
    const int* __restrict__ kptr) {
  const int t = threadIdx.x;
  const int lane = t & 63, wid = t >> 6;
  const int bh = blockIdx.x;
  const int h = bh & (NH - 1);
  __shared__ float xs[LP];
  __shared__ float smp[NL + 2];  // m shifted by 2, zero-padded both ends
  __shared__ int hist[256];
  __shared__ float rs[8];
  __shared__ float fbc[2];
  __shared__ int irs[8];
  __shared__ int ibc[4];

  const float cb = conv_b[h];
  const float* p0 = part + (size_t)bh * NCHUNK * NL;
  float s1 = 0.f, s2 = 0.f;
  for (int i = t; i < LP; i += 256) {
    float v0 = p0[i]           + p0[i + NL];
    float v1 = p0[i + 2 * NL]  + p0[i + 3 * NL];
    float v2 = p0[i + 4 * NL]  + p0[i + 5 * NL];
    float v3 = p0[i + 6 * NL]  + p0[i + 7 * NL];
    float v = ((v0 + v1) + (v2 + v3)) + cb;
    xs[i] = v;
    s1 += v;
    s2 += v * v;
  }
#pragma unroll
  for (int off = 32; off > 0; off >>= 1) {
    s1 += __shfl_down(s1, off);
    s2 += __shfl_down(s2, off);
  }
  if (lane == 0) { rs[wid] = s1; rs[wid + 4] = s2; }
  __syncthreads();
  if (t == 0) {
    float S = rs[0] + rs[1] + rs[2] + rs[3];
    float Q = rs[4] + rs[5] + rs[6] + rs[7];
    float mu = S / (float)LP;
    float var = Q / (float)LP - mu * mu;
    float inv = rsqrtf(var + 1e-5f);
    float sc = bn_gamma[h] * inv;
    fbc[0] = sc;
    fbc[1] = bn_beta[h] - mu * sc;
  }
  __syncthreads();
  {
    const float sc = fbc[0], sh = fbc[1];
    for (int i = t; i < LP; i += 256) xs[i] = fmaf(xs[i], sc, sh);
  }
  // exact radix select of the k-th largest key (4x 8-bit passes)
  int kk = kptr[0];
  const int ktot = kk;
  unsigned prefix = 0, pm = 0;
  for (int pass = 0; pass < 4; ++pass) {
    const int shift = 24 - 8 * pass;
    hist[t] = 0;
    __syncthreads();
    for (int i = t; i < LP; i += 256) {
      unsigned u = fkey(xs[i]);
      if ((u & pm) == prefix) atomicAdd(&hist[(u >> shift) & 255], 1);
    }
    __syncthreads();
    if (t < 64) {  // wave 0: suffix-scan 256 bins, 4 bins/lane
      const int h0 = hist[t * 4 + 0], h1 = hist[t * 4 + 1];
      const int h2 = hist[t * 4 + 2], h3 = hist[t * 4 + 3];
      const int g = h0 + h1 + h2 + h3;
      int sfx = g;
#pragma unroll
      for (int off = 1; off < 64; off <<= 1) {
        int o = __shfl(sfx, (t + off) & 63);
        if (t + off < 64) sfx += o;
      }
      const int A = sfx - g;  // strictly-higher groups
      const int s3 = A + h3, s2i = s3 + h2, s1i = s2i + h1, s0i = s1i + h0;
      int mybin = -1, mykk = 0;
      if (s0i >= kk && s0i - h0 < kk) { mybin = t * 4 + 0; mykk = kk - (s0i - h0); }
      if (s1i >= kk && s1i - h1 < kk) { mybin = t * 4 + 1; mykk = kk - (s1i - h1); }
      if (s2i >= kk && s2i - h2 < kk) { mybin = t * 4 + 2; mykk = kk - (s2i - h2); }
      if (s3  >= kk && s3  - h3 < kk) { mybin = t * 4 + 3; mykk = kk - (s3 - h3); }
      if (mybin >= 0) { ibc[0] = mybin; ibc[1] = mykk; }  // unique crossing
    }
    __syncthreads();
    prefix |= ((unsigned)ibc[0]) << shift;
    pm |= 255u << shift;
    kk = ibc[1];
  }
  const unsigned T = prefix;

  // counts for tie handling
  int cgt = 0, ceq = 0;
  for (int i = t; i < LP; i += 256) {
    unsigned u = fkey(xs[i]);
    cgt += (u > T);
    ceq += (u == T);
  }
#pragma unroll
  for (int off = 32; off > 0; off >>= 1) {
    cgt += __shfl_down(cgt, off);
    ceq += __shfl_down(ceq, off);
  }
  if (lane == 0) { irs[wid] = cgt; irs[wid + 4] = ceq; }
  __syncthreads();
  if (t == 0) {
    ibc[2] = irs[0] + irs[1] + irs[2] + irs[3];
    ibc[3] = irs[4] + irs[5] + irs[6] + irs[7];
  }
  __syncthreads();
  const int need_eq = ktot - ibc[2];
  const bool tie = (ibc[3] != need_eq);

  // mask + sigmoid -> smp (shifted by 2)
  for (int i = t; i < LP; i += 256) {
    float x = xs[i];
    unsigned u = fkey(x);
    bool sel = tie ? (u > T) : (u >= T);
    smp[i + 2] = sel ? 1.f / (1.f + __expf(-x)) : 0.f;
  }
  if (t < 2) { smp[t] = 0.f; smp[NL + t] = 0.f; }
  __syncthreads();
  if (tie && t == 0) {  // rare: stable lowest-index-first like lax.top_k
    int taken = 0;
    for (int i = 0; i < LP && taken < need_eq; ++i) {
      float x = xs[i];
      if (fkey(x) == T) { smp[i + 2] = 1.f / (1.f + __expf(-x)); ++taken; }
    }
  }
  __syncthreads();

  // 3-tap box sum; write this head's gate contribution
  const float cw = comb_w[h] * (1.0f / (float)KW);
  float* row = xi + (size_t)bh * NL;
  for (int l = t; l < NL; l += 256)
    row[l] = cw * ((smp[l + 2] + smp[l + 1]) + smp[l]);
}

// Kernel 3 (new, replaces gate_combine+scale): each thread owns one (b,l4)
// pair and iterates 16 channels. The 8-head gate sum is computed ONCE per
// thread (8 v4f loads from L2-hot xi) then reused across 16 c-iterations
// (1 src load + 1 NT store each, fully coalesced: wave = 64 consecutive l4
// -> 1KB lines). Grid 2048 blocks = 8/CU.
__global__ __launch_bounds__(256) void scale_gate(
    const float* __restrict__ src, const float* __restrict__ xi,
    const float* __restrict__ comb_b, float* __restrict__ out) {
  const int t = threadIdx.x;
  const int cchunk = blockIdx.x >> 7;               // 0..15, 16 channels each
  const int pairidx = (blockIdx.x & 127) * 256 + t; // 0..32767
  const int b = pairidx >> 9;                       // NL/4 = 512 l4 per b
  const int l4 = pairidx & 511;
  const float cb = comb_b[0];

  const v4f* xp = (const v4f*)(xi + (size_t)b * NH * NL) + l4;
  v4f g = xp[0];
#pragma unroll
  for (int h = 1; h < NH; ++h) g += xp[(size_t)h * (NL / 4)];

  const int c0 = cchunk * (NC / 16);
  const v4f* sp = (const v4f*)src + ((size_t)b * NC + c0) * (NL / 4) + l4;
  v4f* op = (v4f*)out + ((size_t)b * NC + c0) * (NL / 4) + l4;
#pragma unroll 4
  for (int c = 0; c < NC / 16; ++c) {
    v4f sv = sp[(size_t)c * (NL / 4)];
    v4f ov;
    ov.x = fmaf(sv.x, g.x, cb);
    ov.y = fmaf(sv.y, g.y, cb);
    ov.z = fmaf(sv.z, g.z, cb);
    ov.w = fmaf(sv.w, g.w, cb);
    __builtin_nontemporal_store(ov, op + (size_t)c * (NL / 4));
  }
}

extern "C" void kernel_launch(void* const* d_in, const int* in_sizes, int n_in,
                              void* d_out, int out_size, void* d_ws, size_t ws_size,
                              hipStream_t stream) {
  const float* src = (const float*)d_in[0];
  const float* conv_w = (const float*)d_in[1];
  const float* conv_b = (const float*)d_in[2];
  const float* bn_gamma = (const float*)d_in[3];
  const float* bn_beta = (const float*)d_in[4];
  const float* comb_w = (const float*)d_in[5];
  const float* comb_b = (const float*)d_in[6];
  const int* kptr = (const int*)d_in[7];
  float* out = (float*)d_out;

  float* xi = (float*)d_ws;  // NB*NH*NL floats (4 MB)
  float* part = out;         // 32 MB scratch inside d_out (consumed by
                             // select_block, then overwritten by scale_gate)

  conv_partial<<<dim3(2, NB, NCHUNK), 256, 0, stream>>>(src, conv_w, part);
  select_block<<<NB * NH, 256, 0, stream>>>(part, xi, conv_b, bn_gamma,
                                            bn_beta, comb_w, kptr);
  scale_gate<<<2048, 256, 0, stream>>>(src, xi, comb_b, out);
}